// Round 5
// baseline (765.300 us; speedup 1.0000x reference)
//
#include <hip/hip_runtime.h>
#include <cstddef>
#include <cstdint>
#include <math.h>

#define N_NODES 50000
#define N_EDGES 1600000
#define IN_C 512
#define HID_C 256
#define OUT_C 50
#define PAD_C 64
#define NUM_LAYERS 10
#define NBLK 196          // ceil(50000/256)
#define NBUCK 98          // ceil(50000/512) row-buckets
#define BSHIFT 9          // 512 rows per bucket
#define BCAP 17408        // mean 16384 + 8 sigma
#define PHB_CHUNK 8192    // edges per block in bucket_scatter
#define PHB_BLOCKS 196    // ceil(N_EDGES / PHB_CHUNK)

typedef __attribute__((ext_vector_type(8))) short short8;    // 8 bf16 (4 VGPRs)
typedef __attribute__((ext_vector_type(4))) float floatx4;   // MFMA C/D frag

__device__ inline unsigned short f2bf(float f) {             // RNE fp32->bf16
    unsigned int u = __float_as_uint(f);
    u += 0x7fffu + ((u >> 16) & 1u);
    return (unsigned short)(u >> 16);
}

// ---------------------------------------------------------------------------
// W1 [512,256] fp32  ->  Wt [256,512] bf16   (LDS-tiled transpose)
// ---------------------------------------------------------------------------
__global__ __launch_bounds__(256) void transpose_w1(const float* __restrict__ W1,
                                                    unsigned short* __restrict__ Wt) {
    __shared__ float tile[32][33];
    int bx = blockIdx.x;               // k-tile (16)
    int by = blockIdx.y;               // n-tile (8)
    int tx = threadIdx.x & 31, ty = threadIdx.x >> 5;   // 32 x 8
#pragma unroll
    for (int i = 0; i < 32; i += 8)
        tile[ty + i][tx] = W1[(bx * 32 + ty + i) * HID_C + by * 32 + tx];
    __syncthreads();
#pragma unroll
    for (int i = 0; i < 32; i += 8)
        Wt[(size_t)(by * 32 + ty + i) * IN_C + bx * 32 + tx] = f2bf(tile[tx][ty + i]);
}

// ---------------------------------------------------------------------------
// GEMM1 MFMA: h_hid[M,256] = relu(x[M,512] @ W1 + b1)
// 64x128 tile, BK=32, bf16 16x16x32 MFMA, register-prefetch double buffering.
// ---------------------------------------------------------------------------
__global__ __launch_bounds__(256) void gemm1_mfma(const float* __restrict__ A,
                                                  const unsigned short* __restrict__ Wt,
                                                  const float* __restrict__ bias,
                                                  float* __restrict__ C) {
    __shared__ unsigned short As[64 * 32];    // [m][k] k-contiguous
    __shared__ unsigned short Bs[128 * 32];   // [n][k] k-contiguous
    const int tid = threadIdx.x;
    const int wave = tid >> 6, lane = tid & 63;
    const int quad = lane >> 4, l16 = lane & 15;
    const int m0 = blockIdx.x * 64, n0 = blockIdx.y * 128;
    const int wm = (wave >> 1) * 32, wn = (wave & 1) * 64;

    floatx4 acc[2][4];
#pragma unroll
    for (int i = 0; i < 2; ++i)
#pragma unroll
        for (int j = 0; j < 4; ++j) acc[i][j] = (floatx4){0.f, 0.f, 0.f, 0.f};

    float4  pa[2];
    ushort4 pb[4];

    auto fetch = [&](int k0) {
#pragma unroll
        for (int j = 0; j < 2; ++j) {
            int row = (j * 256 + tid) >> 3, c = (j * 256 + tid) & 7;
            int gr = m0 + row;
            pa[j] = make_float4(0.f, 0.f, 0.f, 0.f);
            if (gr < N_NODES)
                pa[j] = *(const float4*)(A + (size_t)gr * IN_C + k0 + c * 4);
        }
#pragma unroll
        for (int j = 0; j < 4; ++j) {
            int row = (j * 256 + tid) >> 3, c = (j * 256 + tid) & 7;
            pb[j] = *(const ushort4*)(Wt + (size_t)(n0 + row) * IN_C + k0 + c * 4);
        }
    };

    fetch(0);
    for (int k0 = 0; k0 < IN_C; k0 += 32) {
        __syncthreads();
#pragma unroll
        for (int j = 0; j < 2; ++j) {
            int row = (j * 256 + tid) >> 3, c = (j * 256 + tid) & 7;
            ushort4 u;
            u.x = f2bf(pa[j].x); u.y = f2bf(pa[j].y);
            u.z = f2bf(pa[j].z); u.w = f2bf(pa[j].w);
            *(ushort4*)&As[row * 32 + c * 4] = u;
        }
#pragma unroll
        for (int j = 0; j < 4; ++j) {
            int row = (j * 256 + tid) >> 3, c = (j * 256 + tid) & 7;
            *(ushort4*)&Bs[row * 32 + c * 4] = pb[j];
        }
        __syncthreads();
        if (k0 + 32 < IN_C) fetch(k0 + 32);   // in flight during MFMA phase

        short8 af[2], bf[4];
#pragma unroll
        for (int nt = 0; nt < 4; ++nt)
            bf[nt] = *(const short8*)&Bs[(wn + nt * 16 + l16) * 32 + quad * 8];
#pragma unroll
        for (int mt = 0; mt < 2; ++mt)
            af[mt] = *(const short8*)&As[(wm + mt * 16 + l16) * 32 + quad * 8];
#pragma unroll
        for (int mt = 0; mt < 2; ++mt)
#pragma unroll
            for (int nt = 0; nt < 4; ++nt)
                acc[mt][nt] = __builtin_amdgcn_mfma_f32_16x16x32_bf16(af[mt], bf[nt],
                                                                      acc[mt][nt], 0, 0, 0);
    }

    // epilogue: row = quad*4+r, col = l16 (R3-verified mapping)
#pragma unroll
    for (int nt = 0; nt < 4; ++nt) {
        int n = n0 + wn + nt * 16 + l16;
        float bn = bias[n];
#pragma unroll
        for (int mt = 0; mt < 2; ++mt) {
#pragma unroll
            for (int r = 0; r < 4; ++r) {
                int m = m0 + wm + mt * 16 + quad * 4 + r;
                if (m < N_NODES) {
                    float v = acc[mt][nt][r] + bn;
                    C[(size_t)m * HID_C + n] = v > 0.f ? v : 0.f;
                }
            }
        }
    }
}

// ---------------------------------------------------------------------------
// pad W2 [256,50] -> Wp [256,64] (zeros), b2 -> bp[64]
// ---------------------------------------------------------------------------
__global__ void pad_w2(const float* __restrict__ W2, const float* __restrict__ b2,
                       float* __restrict__ Wp, float* __restrict__ bp) {
    int idx = blockIdx.x * blockDim.x + threadIdx.x;
    if (idx < HID_C * PAD_C) {
        int k = idx >> 6, j = idx & 63;
        Wp[idx] = (j < OUT_C) ? W2[k * OUT_C + j] : 0.f;
    }
    if (idx < PAD_C) bp[idx] = (idx < OUT_C) ? b2[idx] : 0.f;
}

// ---------------------------------------------------------------------------
// GEMM2 tiled: h0 = H[M,256] @ Wp[256,64] + bp ; writes fp32 AND bf16 copies
// ---------------------------------------------------------------------------
__global__ __launch_bounds__(256) void gemm2_tiled(const float* __restrict__ H,
                                                   const float* __restrict__ Wp,
                                                   const float* __restrict__ bp,
                                                   float* __restrict__ h0f,
                                                   unsigned short* __restrict__ h0b) {
    __shared__ float As[16][68];
    __shared__ float Bs[16][64];
    const int tid = threadIdx.x;
    const int tx = tid & 15;
    const int ty = tid >> 4;
    const int m0 = blockIdx.x * 64;

    float acc[4][4];
#pragma unroll
    for (int i = 0; i < 4; ++i)
#pragma unroll
        for (int j = 0; j < 4; ++j) acc[i][j] = 0.f;

    const int arow = tid >> 2;
    const int akk  = (tid & 3) << 2;
    const int brow = tid >> 4;
    const int bcol = (tid & 15) << 2;

    for (int k0 = 0; k0 < HID_C; k0 += 16) {
        float4 av = make_float4(0.f, 0.f, 0.f, 0.f);
        int gr = m0 + arow;
        if (gr < N_NODES)
            av = *(const float4*)(H + (size_t)gr * HID_C + k0 + akk);
        As[akk + 0][arow] = av.x;
        As[akk + 1][arow] = av.y;
        As[akk + 2][arow] = av.z;
        As[akk + 3][arow] = av.w;
        float4 bv = *(const float4*)(Wp + (size_t)(k0 + brow) * PAD_C + bcol);
        *(float4*)&Bs[brow][bcol] = bv;
        __syncthreads();

#pragma unroll
        for (int kk = 0; kk < 16; ++kk) {
            float a[4], b[4];
#pragma unroll
            for (int i = 0; i < 4; ++i) a[i] = As[kk][ty * 4 + i];
#pragma unroll
            for (int j = 0; j < 4; ++j) b[j] = Bs[kk][tx * 4 + j];
#pragma unroll
            for (int i = 0; i < 4; ++i)
#pragma unroll
                for (int j = 0; j < 4; ++j) acc[i][j] = fmaf(a[i], b[j], acc[i][j]);
        }
        __syncthreads();
    }

#pragma unroll
    for (int i = 0; i < 4; ++i) {
        int r = m0 + ty * 4 + i;
        if (r >= N_NODES) continue;
#pragma unroll
        for (int j = 0; j < 4; ++j) {
            int c = tx * 4 + j;
            float v = acc[i][j] + bp[c];
            h0f[(size_t)r * PAD_C + c] = v;
            h0b[(size_t)r * PAD_C + c] = f2bf(v);
        }
    }
}

// ---------------------------------------------------------------------------
// CSR build: histogram + 3-kernel scan + two-phase bucketed scatter.
// R4's direct scatter wrote 8 B to random CSR positions: WRITE_SIZE 102 MB
// (8x amplification, 95 us). Phase B appends edges densely into 98 coarse
// row-buckets (coalesced); phase C scatters each bucket into its contiguous
// ~128 KB CSR span, which stays L2-resident so writebacks merge.
// ---------------------------------------------------------------------------
__global__ void hist_kernel(const int* __restrict__ row, int* __restrict__ cnt) {
    int e = blockIdx.x * blockDim.x + threadIdx.x;
    if (e < N_EDGES) atomicAdd(&cnt[row[e]], 1);
}

__global__ __launch_bounds__(256) void scan1(const int* __restrict__ cnt,
                                             int* __restrict__ rowptr,
                                             int* __restrict__ bsum) {
    __shared__ int sd[256];
    int i = blockIdx.x * 256 + threadIdx.x;
    int v = (i < N_NODES) ? cnt[i] : 0;
    sd[threadIdx.x] = v;
    __syncthreads();
    for (int off = 1; off < 256; off <<= 1) {
        int t = (threadIdx.x >= off) ? sd[threadIdx.x - off] : 0;
        __syncthreads();
        sd[threadIdx.x] += t;
        __syncthreads();
    }
    if (i < N_NODES) rowptr[i] = sd[threadIdx.x] - v;
    if (threadIdx.x == 255) bsum[blockIdx.x] = sd[255];
}

__global__ __launch_bounds__(256) void scan2(const int* __restrict__ bsum,
                                             int* __restrict__ boff,
                                             int* __restrict__ total_out) {
    __shared__ int sd[256];
    int v = (threadIdx.x < NBLK) ? bsum[threadIdx.x] : 0;
    sd[threadIdx.x] = v;
    __syncthreads();
    for (int off = 1; off < 256; off <<= 1) {
        int t = (threadIdx.x >= off) ? sd[threadIdx.x - off] : 0;
        __syncthreads();
        sd[threadIdx.x] += t;
        __syncthreads();
    }
    if (threadIdx.x < NBLK) boff[threadIdx.x] = sd[threadIdx.x] - v;
    if (threadIdx.x == 255) total_out[0] = sd[255];
}

__global__ void scan3(int* __restrict__ rowptr, const int* __restrict__ boff) {
    int i = blockIdx.x * blockDim.x + threadIdx.x;
    if (i < N_NODES) rowptr[i] += boff[blockIdx.x];
}

// Phase B: bin edges into row-buckets. Payload 8 B: (localrow<<17 | col, w).
__global__ __launch_bounds__(256) void bucket_scatter(const int* __restrict__ erow,
                                                      const int* __restrict__ ecol,
                                                      const float* __restrict__ ew,
                                                      const int* __restrict__ rowptr,
                                                      int* __restrict__ fill,
                                                      int* __restrict__ bfill,
                                                      uint2* __restrict__ buckets,
                                                      uint2* __restrict__ edges) {
    __shared__ int lcnt[NBUCK];
    __shared__ int lbase[NBUCK];
    const int t = threadIdx.x;
    for (int b = t; b < NBUCK; b += 256) lcnt[b] = 0;
    __syncthreads();
    const int e0 = blockIdx.x * PHB_CHUNK;
    const int e1 = min(e0 + PHB_CHUNK, N_EDGES);
    for (int e = e0 + t; e < e1; e += 256)
        atomicAdd(&lcnt[erow[e] >> BSHIFT], 1);
    __syncthreads();
    for (int b = t; b < NBUCK; b += 256) {
        lbase[b] = atomicAdd(&bfill[b], lcnt[b]);
        lcnt[b] = 0;
    }
    __syncthreads();
    for (int e = e0 + t; e < e1; e += 256) {
        int r = erow[e];
        int b = r >> BSHIFT;
        int o = atomicAdd(&lcnt[b], 1);
        int idx = lbase[b] + o;
        if (idx < BCAP) {
            unsigned packed = ((unsigned)(r - (b << BSHIFT)) << 17) | (unsigned)ecol[e];
            buckets[(size_t)b * BCAP + idx] = make_uint2(packed, __float_as_uint(ew[e]));
        } else {  // statistically never (cap = mean + 8 sigma); correctness fallback
            int pos = rowptr[r] + atomicAdd(&fill[r], 1);
            edges[pos] = make_uint2((unsigned)ecol[e], __float_as_uint(ew[e]));
        }
    }
}

// Phase C: bucket -> final CSR position (dest span ~128 KB, L2-resident).
__global__ __launch_bounds__(256) void bucket_to_csr(const uint2* __restrict__ buckets,
                                                     const int* __restrict__ bfill,
                                                     const int* __restrict__ rowptr,
                                                     int* __restrict__ fill,
                                                     uint2* __restrict__ edges) {
    int b = blockIdx.x >> 2;          // 4 blocks per bucket
    int part = blockIdx.x & 3;
    int n = min(bfill[b], BCAP);
    for (int i = part * 256 + threadIdx.x; i < n; i += 1024) {
        uint2 t = buckets[(size_t)b * BCAP + i];
        int r = (b << BSHIFT) + (int)(t.x >> 17);
        int pos = rowptr[r] + atomicAdd(&fill[r], 1);
        edges[pos] = make_uint2(t.x & 0x1FFFFu, t.y);
    }
}

// ---------------------------------------------------------------------------
// Propagation, quartet layout: 16 lanes x 8 B (4 bf16 ch) cover one 128 B row,
// 4 lane-quarters process 4 edges per instruction. 32-edge unroll: 8 broadcast
// edge loads issued before 8 gathers -> 8 outstanding gathers per wave.
// ---------------------------------------------------------------------------
template <bool LAST>
__global__ __launch_bounds__(256) void prop_quad(const int* __restrict__ rowptr,
                                                 const uint2* __restrict__ edges,
                                                 const unsigned short* __restrict__ hin,
                                                 const float* __restrict__ h0f,
                                                 unsigned short* __restrict__ hout_b,
                                                 float* __restrict__ hout_f) {
    int wid = (blockIdx.x * blockDim.x + threadIdx.x) >> 6;
    if (wid >= N_NODES) return;
    int lane = threadIdx.x & 63;
    int q  = lane >> 4;      // edge slot within quartet
    int lc = lane & 15;      // 8-byte chunk: channels 4lc .. 4lc+3
    int s = rowptr[wid], e = rowptr[wid + 1];

    float a0[4], a1[4], a2[4], a3[4];
#pragma unroll
    for (int j = 0; j < 4; ++j) { a0[j] = 0.f; a1[j] = 0.f; a2[j] = 0.f; a3[j] = 0.f; }

    int i = s;
    for (; i + 32 <= e; i += 32) {
        uint2 cw[8];
#pragma unroll
        for (int j = 0; j < 8; ++j) cw[j] = edges[i + 4 * j + q];
        uint2 hv[8];
#pragma unroll
        for (int j = 0; j < 8; ++j)
            hv[j] = *(const uint2*)((const char*)hin + ((size_t)cw[j].x << 7) + lc * 8);
#pragma unroll
        for (int j = 0; j < 8; ++j) {
            float w = __uint_as_float(cw[j].y);
            int g = j & 3;
            a0[g] = fmaf(w, __uint_as_float(hv[j].x << 16),         a0[g]);
            a1[g] = fmaf(w, __uint_as_float(hv[j].x & 0xffff0000u), a1[g]);
            a2[g] = fmaf(w, __uint_as_float(hv[j].y << 16),         a2[g]);
            a3[g] = fmaf(w, __uint_as_float(hv[j].y & 0xffff0000u), a3[g]);
        }
    }
    for (; i + 16 <= e; i += 16) {
        uint2 cw[4];
#pragma unroll
        for (int j = 0; j < 4; ++j) cw[j] = edges[i + 4 * j + q];
#pragma unroll
        for (int j = 0; j < 4; ++j) {
            float w = __uint_as_float(cw[j].y);
            uint2 hv = *(const uint2*)((const char*)hin + ((size_t)cw[j].x << 7) + lc * 8);
            a0[j] = fmaf(w, __uint_as_float(hv.x << 16),         a0[j]);
            a1[j] = fmaf(w, __uint_as_float(hv.x & 0xffff0000u), a1[j]);
            a2[j] = fmaf(w, __uint_as_float(hv.y << 16),         a2[j]);
            a3[j] = fmaf(w, __uint_as_float(hv.y & 0xffff0000u), a3[j]);
        }
    }
    for (; i < e; i += 4) {   // masked quartet tail
        int idx = i + q;
        uint2 cw = (idx < e) ? edges[idx] : make_uint2(0u, 0u);
        float w = (idx < e) ? __uint_as_float(cw.y) : 0.f;
        uint2 hv = *(const uint2*)((const char*)hin + ((size_t)cw.x << 7) + lc * 8);
        a0[0] = fmaf(w, __uint_as_float(hv.x << 16),         a0[0]);
        a1[0] = fmaf(w, __uint_as_float(hv.x & 0xffff0000u), a1[0]);
        a2[0] = fmaf(w, __uint_as_float(hv.y << 16),         a2[0]);
        a3[0] = fmaf(w, __uint_as_float(hv.y & 0xffff0000u), a3[0]);
    }

    float s0 = (a0[0] + a0[1]) + (a0[2] + a0[3]);
    float s1 = (a1[0] + a1[1]) + (a1[2] + a1[3]);
    float s2 = (a2[0] + a2[1]) + (a2[2] + a2[3]);
    float s3 = (a3[0] + a3[1]) + (a3[2] + a3[3]);
    s0 += __shfl_xor(s0, 16, 64); s0 += __shfl_xor(s0, 32, 64);
    s1 += __shfl_xor(s1, 16, 64); s1 += __shfl_xor(s1, 32, 64);
    s2 += __shfl_xor(s2, 16, 64); s2 += __shfl_xor(s2, 32, 64);
    s3 += __shfl_xor(s3, 16, 64); s3 += __shfl_xor(s3, 32, 64);

    if (q == 0) {
        size_t off = (size_t)wid * PAD_C + lc * 4;
        float4 h0 = *(const float4*)(h0f + off);
        float r0 = 0.9f * s0 + 0.1f * h0.x;
        float r1 = 0.9f * s1 + 0.1f * h0.y;
        float r2 = 0.9f * s2 + 0.1f * h0.z;
        float r3 = 0.9f * s3 + 0.1f * h0.w;
        if (LAST) {
            *(float4*)(hout_f + off) = make_float4(r0, r1, r2, r3);
        } else {
            ushort4 u;
            u.x = f2bf(r0); u.y = f2bf(r1); u.z = f2bf(r2); u.w = f2bf(r3);
            *(ushort4*)(hout_b + off) = u;
        }
    }
}

// ---------------------------------------------------------------------------
// log_softmax over 50 channels (fp32 input, stride 64), one wave per node
// ---------------------------------------------------------------------------
__global__ __launch_bounds__(256) void logsoftmax_kernel(const float* __restrict__ h,
                                                         float* __restrict__ out) {
    int wave = (blockIdx.x * blockDim.x + threadIdx.x) >> 6;
    int lane = threadIdx.x & 63;
    if (wave >= N_NODES) return;
    float v = (lane < OUT_C) ? h[(size_t)wave * PAD_C + lane] : -INFINITY;
    float m = v;
#pragma unroll
    for (int off = 32; off; off >>= 1) m = fmaxf(m, __shfl_xor(m, off, 64));
    float p = (lane < OUT_C) ? __expf(v - m) : 0.f;
    float ssum = p;
#pragma unroll
    for (int off = 32; off; off >>= 1) ssum += __shfl_xor(ssum, off, 64);
    if (lane < OUT_C) out[(size_t)wave * OUT_C + lane] = (v - m) - __logf(ssum);
}

// ---------------------------------------------------------------------------
extern "C" void kernel_launch(void* const* d_in, const int* in_sizes, int n_in,
                              void* d_out, int out_size, void* d_ws, size_t ws_size,
                              hipStream_t stream) {
    const float* x    = (const float*)d_in[0];
    const int*   erow = (const int*)d_in[1];
    const int*   ecol = (const int*)d_in[2];
    const float* ew   = (const float*)d_in[3];
    const float* W1   = (const float*)d_in[4];
    const float* b1   = (const float*)d_in[5];
    const float* W2   = (const float*)d_in[6];
    const float* b2   = (const float*)d_in[7];
    float* out = (float*)d_out;

    char* p = (char*)d_ws;
    auto alloc = [&](size_t bytes) {
        char* r = p;
        p += (bytes + 255) & ~(size_t)255;
        return r;
    };
    char*  h_hid_raw = alloc((size_t)N_NODES * HID_C * 4);        // 51.2 MB region
    float* h_hid  = (float*)h_hid_raw;
    float* h0f    = (float*)alloc((size_t)N_NODES * PAD_C * 4);   // 12.8 MB
    unsigned short* h0b = (unsigned short*)alloc((size_t)N_NODES * PAD_C * 2); // 6.4 MB
    uint2* edges  = (uint2*)alloc((size_t)N_EDGES * 8);           // 12.8 MB packed CSR
    uint2* buckets= (uint2*)alloc((size_t)NBUCK * BCAP * 8);      // 13.6 MB
    int*   rowptr = (int*)alloc((size_t)(N_NODES + 1) * 4);
    int*   cnt    = (int*)alloc((size_t)N_NODES * 4);
    int*   fill   = (int*)alloc((size_t)N_NODES * 4);
    int*   bfill  = (int*)alloc((size_t)NBUCK * 4);
    int*   bsum   = (int*)alloc((size_t)NBLK * 4);
    int*   boff   = (int*)alloc((size_t)NBLK * 4);
    float* Wp     = (float*)alloc((size_t)HID_C * PAD_C * 4);
    float* bp     = (float*)alloc((size_t)PAD_C * 4);
    unsigned short* Wt = (unsigned short*)alloc((size_t)HID_C * IN_C * 2);
    // alias ping-pong + final buffers onto h_hid region (dead after gemm2)
    unsigned short* ha = (unsigned short*)h_hid_raw;                          // 6.4 MB
    unsigned short* hb = (unsigned short*)(h_hid_raw + (size_t)N_NODES * PAD_C * 2); // 6.4 MB
    float* hfinal = (float*)(h_hid_raw + (size_t)N_NODES * PAD_C * 4);        // 12.8 MB

    hipMemsetAsync(cnt, 0, (size_t)N_NODES * 4, stream);
    hipMemsetAsync(fill, 0, (size_t)N_NODES * 4, stream);
    hipMemsetAsync(bfill, 0, (size_t)NBUCK * 4, stream);

    // CSR build
    hist_kernel<<<(N_EDGES + 255) / 256, 256, 0, stream>>>(erow, cnt);
    scan1<<<NBLK, 256, 0, stream>>>(cnt, rowptr, bsum);
    scan2<<<1, 256, 0, stream>>>(bsum, boff, rowptr + N_NODES);
    scan3<<<NBLK, 256, 0, stream>>>(rowptr, boff);
    bucket_scatter<<<PHB_BLOCKS, 256, 0, stream>>>(erow, ecol, ew, rowptr, fill,
                                                   bfill, buckets, edges);
    bucket_to_csr<<<NBUCK * 4, 256, 0, stream>>>(buckets, bfill, rowptr, fill, edges);

    // MLP
    transpose_w1<<<dim3(IN_C / 32, HID_C / 32), 256, 0, stream>>>(W1, Wt);
    gemm1_mfma<<<dim3((N_NODES + 63) / 64, HID_C / 128), 256, 0, stream>>>(x, Wt, b1, h_hid);
    pad_w2<<<(HID_C * PAD_C + 255) / 256, 256, 0, stream>>>(W2, b2, Wp, bp);
    gemm2_tiled<<<(N_NODES + 63) / 64, 256, 0, stream>>>(h_hid, Wp, bp, h0f, h0b);

    // Propagation x10 (bf16 ping-pong; buffers alias dead h_hid region)
    const int prop_blocks = (N_NODES * 64 + 255) / 256;
    const unsigned short* cur = h0b;
    unsigned short* nxt = ha;
    for (int l = 0; l < NUM_LAYERS - 1; ++l) {
        prop_quad<false><<<prop_blocks, 256, 0, stream>>>(rowptr, edges, cur, h0f,
                                                          nxt, nullptr);
        const unsigned short* t = nxt;
        nxt = (nxt == ha) ? hb : ha;
        cur = t;
    }
    prop_quad<true><<<prop_blocks, 256, 0, stream>>>(rowptr, edges, cur, h0f,
                                                     nullptr, hfinal);

    // log_softmax
    logsoftmax_kernel<<<prop_blocks, 256, 0, stream>>>(hfinal, out);
}

// Round 6
// 716.769 us; speedup vs baseline: 1.0677x; 1.0677x over previous
//
#include <hip/hip_runtime.h>
#include <cstddef>
#include <cstdint>
#include <math.h>

#define N_NODES 50000
#define N_EDGES 1600000
#define IN_C 512
#define HID_C 256
#define OUT_C 50
#define PAD_C 64
#define NUM_LAYERS 10
#define NBLK 196          // ceil(50000/256)
#define NBUCK 98          // ceil(50000/512) row-buckets
#define BSHIFT 9          // 512 rows per bucket
#define BCAP 17408        // mean 16384 + 8 sigma
#define PHB_CHUNK 8192    // edges per block in bucket_scatter
#define PHB_BLOCKS 196    // ceil(N_EDGES / PHB_CHUNK)

typedef __attribute__((ext_vector_type(8))) short short8;    // 8 bf16 (4 VGPRs)
typedef __attribute__((ext_vector_type(4))) float floatx4;   // MFMA C/D frag

__device__ inline unsigned short f2bf(float f) {             // RNE fp32->bf16
    unsigned int u = __float_as_uint(f);
    u += 0x7fffu + ((u >> 16) & 1u);
    return (unsigned short)(u >> 16);
}

// ---------------------------------------------------------------------------
// W1 [512,256] fp32  ->  Wt [256,512] bf16   (LDS-tiled transpose)
// ---------------------------------------------------------------------------
__global__ __launch_bounds__(256) void transpose_w1(const float* __restrict__ W1,
                                                    unsigned short* __restrict__ Wt) {
    __shared__ float tile[32][33];
    int bx = blockIdx.x;               // k-tile (16)
    int by = blockIdx.y;               // n-tile (8)
    int tx = threadIdx.x & 31, ty = threadIdx.x >> 5;   // 32 x 8
#pragma unroll
    for (int i = 0; i < 32; i += 8)
        tile[ty + i][tx] = W1[(bx * 32 + ty + i) * HID_C + by * 32 + tx];
    __syncthreads();
#pragma unroll
    for (int i = 0; i < 32; i += 8)
        Wt[(size_t)(by * 32 + ty + i) * IN_C + bx * 32 + tx] = f2bf(tile[tx][ty + i]);
}

// ---------------------------------------------------------------------------
// GEMM1 MFMA: h_hid[M,256] = relu(x[M,512] @ W1 + b1)
// 64x128 tile, BK=32, bf16 16x16x32 MFMA, register-prefetch double buffering.
// ---------------------------------------------------------------------------
__global__ __launch_bounds__(256) void gemm1_mfma(const float* __restrict__ A,
                                                  const unsigned short* __restrict__ Wt,
                                                  const float* __restrict__ bias,
                                                  float* __restrict__ C) {
    __shared__ unsigned short As[64 * 32];    // [m][k] k-contiguous
    __shared__ unsigned short Bs[128 * 32];   // [n][k] k-contiguous
    const int tid = threadIdx.x;
    const int wave = tid >> 6, lane = tid & 63;
    const int quad = lane >> 4, l16 = lane & 15;
    const int m0 = blockIdx.x * 64, n0 = blockIdx.y * 128;
    const int wm = (wave >> 1) * 32, wn = (wave & 1) * 64;

    floatx4 acc[2][4];
#pragma unroll
    for (int i = 0; i < 2; ++i)
#pragma unroll
        for (int j = 0; j < 4; ++j) acc[i][j] = (floatx4){0.f, 0.f, 0.f, 0.f};

    float4  pa[2];
    ushort4 pb[4];

    auto fetch = [&](int k0) {
#pragma unroll
        for (int j = 0; j < 2; ++j) {
            int row = (j * 256 + tid) >> 3, c = (j * 256 + tid) & 7;
            int gr = m0 + row;
            pa[j] = make_float4(0.f, 0.f, 0.f, 0.f);
            if (gr < N_NODES)
                pa[j] = *(const float4*)(A + (size_t)gr * IN_C + k0 + c * 4);
        }
#pragma unroll
        for (int j = 0; j < 4; ++j) {
            int row = (j * 256 + tid) >> 3, c = (j * 256 + tid) & 7;
            pb[j] = *(const ushort4*)(Wt + (size_t)(n0 + row) * IN_C + k0 + c * 4);
        }
    };

    fetch(0);
    for (int k0 = 0; k0 < IN_C; k0 += 32) {
        __syncthreads();
#pragma unroll
        for (int j = 0; j < 2; ++j) {
            int row = (j * 256 + tid) >> 3, c = (j * 256 + tid) & 7;
            ushort4 u;
            u.x = f2bf(pa[j].x); u.y = f2bf(pa[j].y);
            u.z = f2bf(pa[j].z); u.w = f2bf(pa[j].w);
            *(ushort4*)&As[row * 32 + c * 4] = u;
        }
#pragma unroll
        for (int j = 0; j < 4; ++j) {
            int row = (j * 256 + tid) >> 3, c = (j * 256 + tid) & 7;
            *(ushort4*)&Bs[row * 32 + c * 4] = pb[j];
        }
        __syncthreads();
        if (k0 + 32 < IN_C) fetch(k0 + 32);   // in flight during MFMA phase

        short8 af[2], bf[4];
#pragma unroll
        for (int nt = 0; nt < 4; ++nt)
            bf[nt] = *(const short8*)&Bs[(wn + nt * 16 + l16) * 32 + quad * 8];
#pragma unroll
        for (int mt = 0; mt < 2; ++mt)
            af[mt] = *(const short8*)&As[(wm + mt * 16 + l16) * 32 + quad * 8];
#pragma unroll
        for (int mt = 0; mt < 2; ++mt)
#pragma unroll
            for (int nt = 0; nt < 4; ++nt)
                acc[mt][nt] = __builtin_amdgcn_mfma_f32_16x16x32_bf16(af[mt], bf[nt],
                                                                      acc[mt][nt], 0, 0, 0);
    }

    // epilogue: row = quad*4+r, col = l16 (R3-verified mapping)
#pragma unroll
    for (int nt = 0; nt < 4; ++nt) {
        int n = n0 + wn + nt * 16 + l16;
        float bn = bias[n];
#pragma unroll
        for (int mt = 0; mt < 2; ++mt) {
#pragma unroll
            for (int r = 0; r < 4; ++r) {
                int m = m0 + wm + mt * 16 + quad * 4 + r;
                if (m < N_NODES) {
                    float v = acc[mt][nt][r] + bn;
                    C[(size_t)m * HID_C + n] = v > 0.f ? v : 0.f;
                }
            }
        }
    }
}

// ---------------------------------------------------------------------------
// pad W2 [256,50] -> Wp [256,64] (zeros), b2 -> bp[64]
// ---------------------------------------------------------------------------
__global__ void pad_w2(const float* __restrict__ W2, const float* __restrict__ b2,
                       float* __restrict__ Wp, float* __restrict__ bp) {
    int idx = blockIdx.x * blockDim.x + threadIdx.x;
    if (idx < HID_C * PAD_C) {
        int k = idx >> 6, j = idx & 63;
        Wp[idx] = (j < OUT_C) ? W2[k * OUT_C + j] : 0.f;
    }
    if (idx < PAD_C) bp[idx] = (idx < OUT_C) ? b2[idx] : 0.f;
}

// ---------------------------------------------------------------------------
// GEMM2 tiled: h0 = H[M,256] @ Wp[256,64] + bp ; writes fp32 AND bf16 copies
// ---------------------------------------------------------------------------
__global__ __launch_bounds__(256) void gemm2_tiled(const float* __restrict__ H,
                                                   const float* __restrict__ Wp,
                                                   const float* __restrict__ bp,
                                                   float* __restrict__ h0f,
                                                   unsigned short* __restrict__ h0b) {
    __shared__ float As[16][68];
    __shared__ float Bs[16][64];
    const int tid = threadIdx.x;
    const int tx = tid & 15;
    const int ty = tid >> 4;
    const int m0 = blockIdx.x * 64;

    float acc[4][4];
#pragma unroll
    for (int i = 0; i < 4; ++i)
#pragma unroll
        for (int j = 0; j < 4; ++j) acc[i][j] = 0.f;

    const int arow = tid >> 2;
    const int akk  = (tid & 3) << 2;
    const int brow = tid >> 4;
    const int bcol = (tid & 15) << 2;

    for (int k0 = 0; k0 < HID_C; k0 += 16) {
        float4 av = make_float4(0.f, 0.f, 0.f, 0.f);
        int gr = m0 + arow;
        if (gr < N_NODES)
            av = *(const float4*)(H + (size_t)gr * HID_C + k0 + akk);
        As[akk + 0][arow] = av.x;
        As[akk + 1][arow] = av.y;
        As[akk + 2][arow] = av.z;
        As[akk + 3][arow] = av.w;
        float4 bv = *(const float4*)(Wp + (size_t)(k0 + brow) * PAD_C + bcol);
        *(float4*)&Bs[brow][bcol] = bv;
        __syncthreads();

#pragma unroll
        for (int kk = 0; kk < 16; ++kk) {
            float a[4], b[4];
#pragma unroll
            for (int i = 0; i < 4; ++i) a[i] = As[kk][ty * 4 + i];
#pragma unroll
            for (int j = 0; j < 4; ++j) b[j] = Bs[kk][tx * 4 + j];
#pragma unroll
            for (int i = 0; i < 4; ++i)
#pragma unroll
                for (int j = 0; j < 4; ++j) acc[i][j] = fmaf(a[i], b[j], acc[i][j]);
        }
        __syncthreads();
    }

#pragma unroll
    for (int i = 0; i < 4; ++i) {
        int r = m0 + ty * 4 + i;
        if (r >= N_NODES) continue;
#pragma unroll
        for (int j = 0; j < 4; ++j) {
            int c = tx * 4 + j;
            float v = acc[i][j] + bp[c];
            h0f[(size_t)r * PAD_C + c] = v;
            h0b[(size_t)r * PAD_C + c] = f2bf(v);
        }
    }
}

// ---------------------------------------------------------------------------
// CSR build: histogram + 3-kernel scan + two-phase bucketed scatter (R5-
// verified: killed the 102 MB WRITE_SIZE amplification of direct scatter).
// ---------------------------------------------------------------------------
__global__ void hist_kernel(const int* __restrict__ row, int* __restrict__ cnt) {
    int e = blockIdx.x * blockDim.x + threadIdx.x;
    if (e < N_EDGES) atomicAdd(&cnt[row[e]], 1);
}

__global__ __launch_bounds__(256) void scan1(const int* __restrict__ cnt,
                                             int* __restrict__ rowptr,
                                             int* __restrict__ bsum) {
    __shared__ int sd[256];
    int i = blockIdx.x * 256 + threadIdx.x;
    int v = (i < N_NODES) ? cnt[i] : 0;
    sd[threadIdx.x] = v;
    __syncthreads();
    for (int off = 1; off < 256; off <<= 1) {
        int t = (threadIdx.x >= off) ? sd[threadIdx.x - off] : 0;
        __syncthreads();
        sd[threadIdx.x] += t;
        __syncthreads();
    }
    if (i < N_NODES) rowptr[i] = sd[threadIdx.x] - v;
    if (threadIdx.x == 255) bsum[blockIdx.x] = sd[255];
}

__global__ __launch_bounds__(256) void scan2(const int* __restrict__ bsum,
                                             int* __restrict__ boff,
                                             int* __restrict__ total_out) {
    __shared__ int sd[256];
    int v = (threadIdx.x < NBLK) ? bsum[threadIdx.x] : 0;
    sd[threadIdx.x] = v;
    __syncthreads();
    for (int off = 1; off < 256; off <<= 1) {
        int t = (threadIdx.x >= off) ? sd[threadIdx.x - off] : 0;
        __syncthreads();
        sd[threadIdx.x] += t;
        __syncthreads();
    }
    if (threadIdx.x < NBLK) boff[threadIdx.x] = sd[threadIdx.x] - v;
    if (threadIdx.x == 255) total_out[0] = sd[255];
}

__global__ void scan3(int* __restrict__ rowptr, const int* __restrict__ boff) {
    int i = blockIdx.x * blockDim.x + threadIdx.x;
    if (i < N_NODES) rowptr[i] += boff[blockIdx.x];
}

// Phase B: bin edges into row-buckets. Payload 8 B: (localrow<<17 | col, w).
__global__ __launch_bounds__(256) void bucket_scatter(const int* __restrict__ erow,
                                                      const int* __restrict__ ecol,
                                                      const float* __restrict__ ew,
                                                      const int* __restrict__ rowptr,
                                                      int* __restrict__ fill,
                                                      int* __restrict__ bfill,
                                                      uint2* __restrict__ buckets,
                                                      uint2* __restrict__ edges) {
    __shared__ int lcnt[NBUCK];
    __shared__ int lbase[NBUCK];
    const int t = threadIdx.x;
    for (int b = t; b < NBUCK; b += 256) lcnt[b] = 0;
    __syncthreads();
    const int e0 = blockIdx.x * PHB_CHUNK;
    const int e1 = min(e0 + PHB_CHUNK, N_EDGES);
    for (int e = e0 + t; e < e1; e += 256)
        atomicAdd(&lcnt[erow[e] >> BSHIFT], 1);
    __syncthreads();
    for (int b = t; b < NBUCK; b += 256) {
        lbase[b] = atomicAdd(&bfill[b], lcnt[b]);
        lcnt[b] = 0;
    }
    __syncthreads();
    for (int e = e0 + t; e < e1; e += 256) {
        int r = erow[e];
        int b = r >> BSHIFT;
        int o = atomicAdd(&lcnt[b], 1);
        int idx = lbase[b] + o;
        if (idx < BCAP) {
            unsigned packed = ((unsigned)(r - (b << BSHIFT)) << 17) | (unsigned)ecol[e];
            buckets[(size_t)b * BCAP + idx] = make_uint2(packed, __float_as_uint(ew[e]));
        } else {  // statistically never (cap = mean + 8 sigma); correctness fallback
            int pos = rowptr[r] + atomicAdd(&fill[r], 1);
            edges[pos] = make_uint2((unsigned)ecol[e], __float_as_uint(ew[e]));
        }
    }
}

// Phase C: bucket -> final CSR position (dest span ~128 KB, L2-resident).
__global__ __launch_bounds__(256) void bucket_to_csr(const uint2* __restrict__ buckets,
                                                     const int* __restrict__ bfill,
                                                     const int* __restrict__ rowptr,
                                                     int* __restrict__ fill,
                                                     uint2* __restrict__ edges) {
    int b = blockIdx.x >> 2;          // 4 blocks per bucket
    int part = blockIdx.x & 3;
    int n = min(bfill[b], BCAP);
    for (int i = part * 256 + threadIdx.x; i < n; i += 1024) {
        uint2 t = buckets[(size_t)b * BCAP + i];
        int r = (b << BSHIFT) + (int)(t.x >> 17);
        int pos = rowptr[r] + atomicAdd(&fill[r], 1);
        edges[pos] = make_uint2(t.x & 0x1FFFFu, t.y);
    }
}

// ---------------------------------------------------------------------------
// Propagation, 8-lane layout: lane covers 16 B (8 bf16 ch) via dwordx4, 8
// lanes cover one 128 B row -> ONE gather instruction serves 8 edges (1 KB).
// Unroll x2 -> 2 KB in flight/wave, half the VMEM instr count of R4/R5.
// xor(8/16/32) butterfly = all-reduce, so every lane holds the final row;
// LAST layer fuses log_softmax in-register (xor 1/2/4 over the 8-lane group)
// and writes d_out directly — no hfinal round-trip, no separate kernel.
// ---------------------------------------------------------------------------
template <bool LAST>
__global__ __launch_bounds__(256) void prop8(const int* __restrict__ rowptr,
                                             const uint2* __restrict__ edges,
                                             const unsigned short* __restrict__ hin,
                                             const float* __restrict__ h0f,
                                             unsigned short* __restrict__ hout_b,
                                             float* __restrict__ out_f) {
    int wid = (blockIdx.x * blockDim.x + threadIdx.x) >> 6;
    if (wid >= N_NODES) return;
    int lane = threadIdx.x & 63;
    int slot = lane >> 3;     // edge slot (8 per instruction)
    int lc   = lane & 7;      // 16 B chunk: channels 8lc .. 8lc+7
    int s = rowptr[wid], e = rowptr[wid + 1];

    float acc0[8], acc1[8];
#pragma unroll
    for (int k = 0; k < 8; ++k) { acc0[k] = 0.f; acc1[k] = 0.f; }

    int i = s;
    for (; i + 16 <= e; i += 16) {
        uint2 cw0 = edges[i + slot];
        uint2 cw1 = edges[i + 8 + slot];
        uint4 hv0 = *(const uint4*)((const char*)hin + ((size_t)cw0.x << 7) + lc * 16);
        uint4 hv1 = *(const uint4*)((const char*)hin + ((size_t)cw1.x << 7) + lc * 16);
        float w0 = __uint_as_float(cw0.y);
        float w1 = __uint_as_float(cw1.y);
        acc0[0] = fmaf(w0, __uint_as_float(hv0.x << 16),         acc0[0]);
        acc0[1] = fmaf(w0, __uint_as_float(hv0.x & 0xffff0000u), acc0[1]);
        acc0[2] = fmaf(w0, __uint_as_float(hv0.y << 16),         acc0[2]);
        acc0[3] = fmaf(w0, __uint_as_float(hv0.y & 0xffff0000u), acc0[3]);
        acc0[4] = fmaf(w0, __uint_as_float(hv0.z << 16),         acc0[4]);
        acc0[5] = fmaf(w0, __uint_as_float(hv0.z & 0xffff0000u), acc0[5]);
        acc0[6] = fmaf(w0, __uint_as_float(hv0.w << 16),         acc0[6]);
        acc0[7] = fmaf(w0, __uint_as_float(hv0.w & 0xffff0000u), acc0[7]);
        acc1[0] = fmaf(w1, __uint_as_float(hv1.x << 16),         acc1[0]);
        acc1[1] = fmaf(w1, __uint_as_float(hv1.x & 0xffff0000u), acc1[1]);
        acc1[2] = fmaf(w1, __uint_as_float(hv1.y << 16),         acc1[2]);
        acc1[3] = fmaf(w1, __uint_as_float(hv1.y & 0xffff0000u), acc1[3]);
        acc1[4] = fmaf(w1, __uint_as_float(hv1.z << 16),         acc1[4]);
        acc1[5] = fmaf(w1, __uint_as_float(hv1.z & 0xffff0000u), acc1[5]);
        acc1[6] = fmaf(w1, __uint_as_float(hv1.w << 16),         acc1[6]);
        acc1[7] = fmaf(w1, __uint_as_float(hv1.w & 0xffff0000u), acc1[7]);
    }
    for (; i < e; i += 8) {     // masked tail (covers 1 full + 1 partial group)
        int idx = i + slot;
        uint2 cw = (idx < e) ? edges[idx] : make_uint2(0u, 0u);
        float w  = (idx < e) ? __uint_as_float(cw.y) : 0.f;
        uint4 hv = *(const uint4*)((const char*)hin + ((size_t)cw.x << 7) + lc * 16);
        acc0[0] = fmaf(w, __uint_as_float(hv.x << 16),         acc0[0]);
        acc0[1] = fmaf(w, __uint_as_float(hv.x & 0xffff0000u), acc0[1]);
        acc0[2] = fmaf(w, __uint_as_float(hv.y << 16),         acc0[2]);
        acc0[3] = fmaf(w, __uint_as_float(hv.y & 0xffff0000u), acc0[3]);
        acc0[4] = fmaf(w, __uint_as_float(hv.z << 16),         acc0[4]);
        acc0[5] = fmaf(w, __uint_as_float(hv.z & 0xffff0000u), acc0[5]);
        acc0[6] = fmaf(w, __uint_as_float(hv.w << 16),         acc0[6]);
        acc0[7] = fmaf(w, __uint_as_float(hv.w & 0xffff0000u), acc0[7]);
    }

    float r[8];
#pragma unroll
    for (int k = 0; k < 8; ++k) {
        float v = acc0[k] + acc1[k];
        v += __shfl_xor(v, 8, 64);    // butterfly over edge slots = all-reduce:
        v += __shfl_xor(v, 16, 64);   // every lane ends with the full row sum
        v += __shfl_xor(v, 32, 64);
        r[k] = v;
    }

    size_t off = (size_t)wid * PAD_C + lc * 8;
    float4 h0a = *(const float4*)(h0f + off);
    float4 h0b4 = *(const float4*)(h0f + off + 4);
    r[0] = 0.9f * r[0] + 0.1f * h0a.x;  r[1] = 0.9f * r[1] + 0.1f * h0a.y;
    r[2] = 0.9f * r[2] + 0.1f * h0a.z;  r[3] = 0.9f * r[3] + 0.1f * h0a.w;
    r[4] = 0.9f * r[4] + 0.1f * h0b4.x; r[5] = 0.9f * r[5] + 0.1f * h0b4.y;
    r[6] = 0.9f * r[6] + 0.1f * h0b4.z; r[7] = 0.9f * r[7] + 0.1f * h0b4.w;

    if (!LAST) {
        if (slot == 0) {
            uint4 u;
            u.x = ((unsigned)f2bf(r[1]) << 16) | f2bf(r[0]);
            u.y = ((unsigned)f2bf(r[3]) << 16) | f2bf(r[2]);
            u.z = ((unsigned)f2bf(r[5]) << 16) | f2bf(r[4]);
            u.w = ((unsigned)f2bf(r[7]) << 16) | f2bf(r[6]);
            *(uint4*)((char*)hout_b + ((size_t)wid << 7) + lc * 16) = u;
        }
    } else {
        // fused log_softmax over ch 0..49 (all lanes compute; shuffles xor
        // lc bits only, staying within each 8-lane slot group)
        int ch0 = lc * 8;
        float m = -INFINITY;
#pragma unroll
        for (int k = 0; k < 8; ++k) if (ch0 + k < OUT_C) m = fmaxf(m, r[k]);
        m = fmaxf(m, __shfl_xor(m, 1, 64));
        m = fmaxf(m, __shfl_xor(m, 2, 64));
        m = fmaxf(m, __shfl_xor(m, 4, 64));
        float ss = 0.f;
#pragma unroll
        for (int k = 0; k < 8; ++k) if (ch0 + k < OUT_C) ss += __expf(r[k] - m);
        ss += __shfl_xor(ss, 1, 64);
        ss += __shfl_xor(ss, 2, 64);
        ss += __shfl_xor(ss, 4, 64);
        float lse = __logf(ss);
        if (slot == 0) {
#pragma unroll
            for (int k = 0; k < 8; ++k)
                if (ch0 + k < OUT_C)
                    out_f[(size_t)wid * OUT_C + ch0 + k] = (r[k] - m) - lse;
        }
    }
}

// ---------------------------------------------------------------------------
extern "C" void kernel_launch(void* const* d_in, const int* in_sizes, int n_in,
                              void* d_out, int out_size, void* d_ws, size_t ws_size,
                              hipStream_t stream) {
    const float* x    = (const float*)d_in[0];
    const int*   erow = (const int*)d_in[1];
    const int*   ecol = (const int*)d_in[2];
    const float* ew   = (const float*)d_in[3];
    const float* W1   = (const float*)d_in[4];
    const float* b1   = (const float*)d_in[5];
    const float* W2   = (const float*)d_in[6];
    const float* b2   = (const float*)d_in[7];
    float* out = (float*)d_out;

    char* p = (char*)d_ws;
    auto alloc = [&](size_t bytes) {
        char* r = p;
        p += (bytes + 255) & ~(size_t)255;
        return r;
    };
    char*  h_hid_raw = alloc((size_t)N_NODES * HID_C * 4);        // 51.2 MB region
    float* h_hid  = (float*)h_hid_raw;
    float* h0f    = (float*)alloc((size_t)N_NODES * PAD_C * 4);   // 12.8 MB
    unsigned short* h0b = (unsigned short*)alloc((size_t)N_NODES * PAD_C * 2); // 6.4 MB
    uint2* edges  = (uint2*)alloc((size_t)N_EDGES * 8);           // 12.8 MB packed CSR
    uint2* buckets= (uint2*)alloc((size_t)NBUCK * BCAP * 8);      // 13.6 MB
    int*   rowptr = (int*)alloc((size_t)(N_NODES + 1) * 4);
    int*   cnt    = (int*)alloc((size_t)N_NODES * 4);
    int*   fill   = (int*)alloc((size_t)N_NODES * 4);
    int*   bfill  = (int*)alloc((size_t)NBUCK * 4);
    int*   bsum   = (int*)alloc((size_t)NBLK * 4);
    int*   boff   = (int*)alloc((size_t)NBLK * 4);
    float* Wp     = (float*)alloc((size_t)HID_C * PAD_C * 4);
    float* bp     = (float*)alloc((size_t)PAD_C * 4);
    unsigned short* Wt = (unsigned short*)alloc((size_t)HID_C * IN_C * 2);
    // alias ping-pong buffers onto h_hid region (dead after gemm2)
    unsigned short* ha = (unsigned short*)h_hid_raw;                          // 6.4 MB
    unsigned short* hb = (unsigned short*)(h_hid_raw + (size_t)N_NODES * PAD_C * 2); // 6.4 MB

    hipMemsetAsync(cnt, 0, (size_t)N_NODES * 4, stream);
    hipMemsetAsync(fill, 0, (size_t)N_NODES * 4, stream);
    hipMemsetAsync(bfill, 0, (size_t)NBUCK * 4, stream);

    // CSR build
    hist_kernel<<<(N_EDGES + 255) / 256, 256, 0, stream>>>(erow, cnt);
    scan1<<<NBLK, 256, 0, stream>>>(cnt, rowptr, bsum);
    scan2<<<1, 256, 0, stream>>>(bsum, boff, rowptr + N_NODES);
    scan3<<<NBLK, 256, 0, stream>>>(rowptr, boff);
    bucket_scatter<<<PHB_BLOCKS, 256, 0, stream>>>(erow, ecol, ew, rowptr, fill,
                                                   bfill, buckets, edges);
    bucket_to_csr<<<NBUCK * 4, 256, 0, stream>>>(buckets, bfill, rowptr, fill, edges);

    // MLP
    transpose_w1<<<dim3(IN_C / 32, HID_C / 32), 256, 0, stream>>>(W1, Wt);
    gemm1_mfma<<<dim3((N_NODES + 63) / 64, HID_C / 128), 256, 0, stream>>>(x, Wt, b1, h_hid);
    pad_w2<<<(HID_C * PAD_C + 255) / 256, 256, 0, stream>>>(W2, b2, Wp, bp);
    gemm2_tiled<<<(N_NODES + 63) / 64, 256, 0, stream>>>(h_hid, Wp, bp, h0f, h0b);

    // Propagation x10 (bf16 ping-pong; last layer fuses log_softmax -> out)
    const int prop_blocks = (N_NODES * 64 + 255) / 256;
    const unsigned short* cur = h0b;
    unsigned short* nxt = ha;
    for (int l = 0; l < NUM_LAYERS - 1; ++l) {
        prop8<false><<<prop_blocks, 256, 0, stream>>>(rowptr, edges, cur, h0f,
                                                      nxt, nullptr);
        const unsigned short* t = nxt;
        nxt = (nxt == ha) ? hb : ha;
        cur = t;
    }
    prop8<true><<<prop_blocks, 256, 0, stream>>>(rowptr, edges, cur, h0f,
                                                 nullptr, out);
}